// Round 3
// baseline (131.773 us; speedup 1.0000x reference)
//
#include <hip/hip_runtime.h>

#define B 16384
#define N_SPARSE 16
#define N_VARLEN 4
#define L 50
#define V 1000000
#define ROW (N_SPARSE + N_VARLEN * L)   // 216 ids per row
#define OUT_W (N_SPARSE + N_VARLEN)     // 20 floats per row
#define KLANES 8                        // lanes cooperating per (row, varlen feature)

// Grid layout (XCD = blockIdx % 8 on MI355X, 8 XCDs):
//   blocks [0, 2048):    varlen pooling. xcd = bid&7 -> feature f = xcd&3,
//                        row-half = xcd>>2. Each XCD's 4MB L2 caches exactly
//                        one ~3.8MB varlen table.
//                        NEW: each block streams a 16KB slice of its table into
//                        L2 via fire-and-forget global_load_lds (poison fills
//                        wipe L2+L3 between replays, so tables must be re-warmed
//                        every dispatch — stream them at full HBM BW instead of
//                        paying random 64B demand misses).
//   blocks [2048, 3072): sparse gathers, 16 rows x 16 features per block,
//                        all traffic non-temporal (no L2 pollution).
#define VARLEN_BLOCKS 2048
#define SPARSE_BLOCKS 1024

__global__ __launch_bounds__(256) void emb_gather_pool_kernel(
    const int* __restrict__ X,
    const float* __restrict__ sparse_tables,
    const float* __restrict__ varlen_tables,
    float* __restrict__ out)
{
    const int bid = blockIdx.x;
    const int t   = threadIdx.x;

    if (bid < VARLEN_BLOCKS) {
        // ---- varlen masked-mean pooling, XCD-pinned per table ----
        const int xcd  = bid & 7;
        const int f    = xcd & 3;        // table f on XCDs f and f+4
        const int half = xcd >> 2;       // which half of the rows
        const int slot = bid >> 3;       // [0,256) row-chunk within (f, half)
        const int task = t >> 3;         // [0,32) row within block
        const int lane = t & (KLANES - 1);
        const int row  = half * (B / 2) + slot * 32 + task;

        const int*   ids = X + row * ROW + N_SPARSE + f * L;
        const float* tab = varlen_tables + (long)f * V;

        // ---- streamed L2 prefetch of this block's 16KB table slice ----
        // Fire-and-forget: dest is a raced LDS sink we never read, so the
        // compiler emits no waitcnt for these; they just warm this XCD's L2.
        __shared__ float pf_sink[256];   // 1KB: 64 lanes x 16B per wave-op
        {
            const int base = slot * 4096 + t * 4;   // float index into table
            #pragma unroll
            for (int c = 0; c < 4; ++c) {
                const int g = base + c * 1024;
                if (g + 4 <= V) {
                    __builtin_amdgcn_global_load_lds(
                        (const __attribute__((address_space(1))) void*)(tab + g),
                        (__attribute__((address_space(3))) void*)pf_sink,
                        16, 0, 0);
                }
            }
        }

        float sum = 0.0f;
        float cnt = 0.0f;
        #pragma unroll
        for (int l = lane; l < L; l += KLANES) {
            const int id = __builtin_nontemporal_load(ids + l);  // streamed once
            const float v = tab[id];                              // L2 hit (warm)
            const float m = (id != 0) ? 1.0f : 0.0f;
            sum = fmaf(m, v, sum);
            cnt += m;
        }

        #pragma unroll
        for (int off = 1; off < KLANES; off <<= 1) {
            sum += __shfl_xor(sum, off);
            cnt += __shfl_xor(cnt, off);
        }

        if (lane == 0) {
            __builtin_nontemporal_store(sum / (cnt + 1e-8f),
                                        out + row * OUT_W + N_SPARSE + f);
        }
    } else {
        // ---- sparse single gathers, fully streaming (non-temporal) ----
        const int sb  = bid - VARLEN_BLOCKS;   // [0,1024)
        const int rl  = t >> 4;                // row within block [0,16)
        const int j   = t & 15;                // sparse feature
        const int row = sb * 16 + rl;

        const int   id = __builtin_nontemporal_load(X + row * ROW + j);
        const float v  = __builtin_nontemporal_load(sparse_tables + (long)j * V + id);
        __builtin_nontemporal_store(v, out + row * OUT_W + j);
    }
}

extern "C" void kernel_launch(void* const* d_in, const int* in_sizes, int n_in,
                              void* d_out, int out_size, void* d_ws, size_t ws_size,
                              hipStream_t stream) {
    const int*   X             = (const int*)  d_in[0];
    const float* sparse_tables = (const float*)d_in[1];
    const float* varlen_tables = (const float*)d_in[2];
    float*       out           = (float*)d_out;

    const int grid  = VARLEN_BLOCKS + SPARSE_BLOCKS;   // 3072
    const int block = 256;

    emb_gather_pool_kernel<<<grid, block, 0, stream>>>(X, sparse_tables, varlen_tables, out);
}

// Round 4
// 127.638 us; speedup vs baseline: 1.0324x; 1.0324x over previous
//
#include <hip/hip_runtime.h>

#define B 16384
#define N_SPARSE 16
#define N_VARLEN 4
#define L 50
#define V 1000000
#define ROW (N_SPARSE + N_VARLEN * L)   // 216 ids per row
#define OUT_W (N_SPARSE + N_VARLEN)     // 20 floats per row
#define KLANES 8                        // lanes cooperating per (row, varlen feature)
#define NITER 7                         // ceil(L / KLANES), uniform trip count

// Grid layout (XCD = blockIdx % 8 on MI355X):
//   blocks [0, 2048):    varlen pooling, table f pinned to XCDs {f, f+4}
//                        (each XCD's 4MB L2 caches one ~3.8MB varlen table;
//                        ~13x reuse per line per dispatch).
//   blocks [2048, 3072): sparse gathers, fully non-temporal (no L2 pollution
//                        of the pinned varlen tables).
// ILP: all per-lane id loads and table gathers are issued in fully-unrolled
// batches (uniform trip count + predication) -> ~7 outstanding random misses
// per lane instead of a serialized load->gather chain per iteration.
#define VARLEN_BLOCKS 2048
#define SPARSE_BLOCKS 1024

__global__ __launch_bounds__(256) void emb_gather_pool_kernel(
    const int* __restrict__ X,
    const float* __restrict__ sparse_tables,
    const float* __restrict__ varlen_tables,
    float* __restrict__ out)
{
    const int bid = blockIdx.x;
    const int t   = threadIdx.x;

    if (bid < VARLEN_BLOCKS) {
        // ---- varlen masked-mean pooling, XCD-pinned per table ----
        const int xcd  = bid & 7;
        const int f    = xcd & 3;        // table f on XCDs f and f+4
        const int half = xcd >> 2;       // which half of the rows
        const int slot = bid >> 3;       // [0,256) row-chunk within (f, half)
        const int task = t >> 3;         // [0,32) row within block
        const int lane = t & (KLANES - 1);
        const int row  = half * (B / 2) + slot * 32 + task;

        const int*   ids = X + row * ROW + N_SPARSE + f * L;
        const float* tab = varlen_tables + (long)f * V;

        // Phase 1: issue ALL id loads (independent, coalesced across lanes).
        // OOB slots (l >= 50, only at k=6 lanes 2..7) get id=0, which the
        // id!=0 mask nullifies below -> exact reference semantics.
        int id[NITER];
        #pragma unroll
        for (int k = 0; k < NITER; ++k) {
            const int l = lane + k * KLANES;
            id[k] = (l < L) ? __builtin_nontemporal_load(ids + l) : 0;
        }

        // Phase 2: issue ALL table gathers (7 outstanding misses per lane).
        float v[NITER];
        #pragma unroll
        for (int k = 0; k < NITER; ++k) {
            v[k] = tab[id[k]];           // normal load: keep lines in L2
        }

        // Phase 3: branch-free masked accumulate.
        float sum = 0.0f;
        float cnt = 0.0f;
        #pragma unroll
        for (int k = 0; k < NITER; ++k) {
            const float m = (id[k] != 0) ? 1.0f : 0.0f;
            sum = fmaf(m, v[k], sum);
            cnt += m;
        }

        // Reduce across the aligned 8-lane group.
        #pragma unroll
        for (int off = 1; off < KLANES; off <<= 1) {
            sum += __shfl_xor(sum, off);
            cnt += __shfl_xor(cnt, off);
        }

        if (lane == 0) {
            __builtin_nontemporal_store(sum / (cnt + 1e-8f),
                                        out + row * OUT_W + N_SPARSE + f);
        }
    } else {
        // ---- sparse single gathers, fully streaming (non-temporal) ----
        const int sb  = bid - VARLEN_BLOCKS;   // [0,1024)
        const int rl  = t >> 4;                // row within block [0,16)
        const int j   = t & 15;                // sparse feature
        const int row = sb * 16 + rl;

        const int   id = __builtin_nontemporal_load(X + row * ROW + j);
        const float v  = __builtin_nontemporal_load(sparse_tables + (long)j * V + id);
        __builtin_nontemporal_store(v, out + row * OUT_W + j);
    }
}

extern "C" void kernel_launch(void* const* d_in, const int* in_sizes, int n_in,
                              void* d_out, int out_size, void* d_ws, size_t ws_size,
                              hipStream_t stream) {
    const int*   X             = (const int*)  d_in[0];
    const float* sparse_tables = (const float*)d_in[1];
    const float* varlen_tables = (const float*)d_in[2];
    float*       out           = (float*)d_out;

    const int grid  = VARLEN_BLOCKS + SPARSE_BLOCKS;   // 3072
    const int block = 256;

    emb_gather_pool_kernel<<<grid, block, 0, stream>>>(X, sparse_tables, varlen_tables, out);
}